// Round 19
// baseline (202.541 us; speedup 1.0000x reference)
//
#include <hip/hip_runtime.h>
#include <cstdint>
#include <cstddef>

// Qwen3AttentionModified: B=1 S=2048 D=2048 H=16 KVH=8 HD=128
// v19: GEMMs -> 256x128 tile, 4 waves (per-wave 128x64: 32 MFMA / 12 ds_reads,
// ratio 2.67 vs 2.0), 3-stage counted-vmcnt pipeline (72KB LDS, 1 block/CU).
// QKV: grid (8,32), bf16 out. O: split-K2 grid (8,16,2), fp32 partials + ored.
// attn v13 (dual-Q + key-parity, r18-verified), ared, rope, vtr, cast, tw unchanged.

namespace {
constexpr int kS = 2048;
constexpr int kD = 2048;
constexpr int kH = 16;
constexpr int kKVH = 8;
constexpr int kHD = 128;
constexpr float kScale = 0.08838834764831845f;  // 128^-0.5
constexpr size_t MB = 1u << 20;
}  // namespace

using f32x4 = __attribute__((ext_vector_type(4))) float;
using bfrag = __attribute__((ext_vector_type(8))) short;   // 8 x bf16 (16B)
using float4v = __attribute__((ext_vector_type(4))) float;
using short4v = __attribute__((ext_vector_type(4))) short;

__device__ __forceinline__ unsigned short f2b(float f) {
  union { float f; unsigned u; } x; x.f = f;
  unsigned r = x.u + 0x7FFFu + ((x.u >> 16) & 1u);  // RNE
  return (unsigned short)(r >> 16);
}

__device__ __forceinline__ float b2f(unsigned short u) {
  union { unsigned u; float f; } x; x.u = ((unsigned)u) << 16;
  return x.f;
}

__device__ __forceinline__ void gload_lds16(const void* g, void* l) {
  __builtin_amdgcn_global_load_lds(
      (const __attribute__((address_space(1))) unsigned*)g,
      (__attribute__((address_space(3))) unsigned*)l, 16, 0, 0);
}

// ---------------- cast fp32 -> bf16, GEMM-swizzled store ----------------
__global__ __launch_bounds__(256) void qwen_cast_bf16(const float* __restrict__ in,
                                                      unsigned short* __restrict__ out,
                                                      int n4) {
  int i = blockIdx.x * 256 + threadIdx.x;
  if (i >= n4) return;
  float4v v = *(const float4v*)(in + (size_t)i * 4);
  short4v o;
  o[0] = (short)f2b(v[0]); o[1] = (short)f2b(v[1]);
  o[2] = (short)f2b(v[2]); o[3] = (short)f2b(v[3]);
  int i4 = i * 4;
  int row = i4 >> 11, col = i4 & 2047;
  int scol = col ^ ((row & 3) << 3);
  *(short4v*)(out + ((size_t)row << 11) + scol) = o;
}

// ------------- transpose + cast: fp32 [R][C] -> bf16 [C][ldo], swizzled store -------------
__global__ __launch_bounds__(256) void qwen_tw(const float* __restrict__ in, int R, int C,
                                               unsigned short* __restrict__ out, int ldo) {
  __shared__ float t[64][65];
  int c0 = blockIdx.x * 64, r0 = blockIdx.y * 64;
  int tr = threadIdx.x >> 6, tc = threadIdx.x & 63;
#pragma unroll
  for (int p = 0; p < 16; ++p) {
    int i = p * 4 + tr;
    t[i][tc] = in[(size_t)(r0 + i) * C + c0 + tc];
  }
  __syncthreads();
#pragma unroll
  for (int p = 0; p < 16; ++p) {
    int i = p * 4 + tr;
    int orow = c0 + i;
    int ocol = r0 + tc;
    int scol = ocol ^ ((orow & 3) << 3);
    out[(size_t)orow * ldo + scol] = f2b(t[tc][i]);
  }
}

// ------------- GEMM v19: 256x128 tile, 4 waves, 3-stage counted pipeline -------------
// A[M][Kfull], Bt[N][Kfull] bf16 with col^((row&3)<<3) swizzle; k-slice [k0,k0+KS).
// Wave (wr,wc) of 2x2 owns 128x64 out: acc[8][4]. Per iter: 12 ds_read_b128 ->
// 32 MFMA. Pipeline: stage(0),stage(1); iter t: vmcnt(6) [stage(t) landed,
// stage(t+1) in flight] -> barrier -> stage(t+2,(t+2)%3) -> compute buf t%3.
// OUTMODE 0: bf16 store. OUTMODE 1: fp32 partial at Cv + z*M*N.
template <int OUTMODE>
__global__ __launch_bounds__(256, 1) void qwen_gemm_big(const unsigned short* __restrict__ A,
                                                        const unsigned short* __restrict__ Bt,
                                                        void* __restrict__ Cv,
                                                        int M, int N, int Kfull, int KS) {
  __shared__ unsigned short As[3][256 * 32];  // 48KB
  __shared__ unsigned short Bs[3][128 * 32];  // 24KB
  const int nwg = gridDim.x * gridDim.y;      // multiple of 8
  int lin = blockIdx.y * gridDim.x + blockIdx.x;
  { int qq = nwg >> 3; lin = (lin & 7) * qq + (lin >> 3); }
  const int bxx = lin % gridDim.x, byy = lin / gridDim.x;
  const int k0 = blockIdx.z * KS;
  const int tid = threadIdx.x, lane = tid & 63, w = tid >> 6;
  const int wr = w >> 1, wc = w & 1;
  const int row0 = bxx * 256, col0 = byy * 128;
  f32x4 acc[8][4] = {};
  const int koff = (lane >> 4) << 3;
  const int kread = koff ^ ((lane & 3) << 3);
  const int rA = wr * 128 + (lane & 15);
  const int rB = wc * 64 + (lane & 15);

  auto stage = [&](int kt, int b) {
#pragma unroll
    for (int c = 0; c < 4; ++c) {  // A: 256 rows x 32
      int off = (c * 256 + tid) * 16;
      int e = off >> 1;
      int r = e >> 5, cc = e & 31;
      gload_lds16(A + (size_t)(row0 + r) * Kfull + k0 + kt + cc, (char*)(&As[b][0]) + off);
    }
#pragma unroll
    for (int c = 0; c < 2; ++c) {  // B: 128 rows x 32
      int off = (c * 256 + tid) * 16;
      int e = off >> 1;
      int r = e >> 5, cc = e & 31;
      gload_lds16(Bt + (size_t)(col0 + r) * Kfull + k0 + kt + cc, (char*)(&Bs[b][0]) + off);
    }
  };

  const int nk = KS >> 5;
  stage(0, 0);
  stage(32, 1);
#pragma unroll 1
  for (int t = 0; t < nk; ++t) {
    if (t + 1 < nk) {
      asm volatile("s_waitcnt vmcnt(6)" ::: "memory");  // stage(t) landed; t+1 in flight
    } else {
      asm volatile("s_waitcnt vmcnt(0)" ::: "memory");
    }
    __builtin_amdgcn_s_barrier();  // all waves: stage(t) visible + done reading buf[(t+2)%3]
    if (t + 2 < nk) stage((t + 2) << 5, (t + 2) % 3);
    const int buf = t % 3;
    bfrag aF[8], bF[4];
#pragma unroll
    for (int m = 0; m < 8; ++m)
      aF[m] = *(const bfrag*)(&As[buf][0] + (rA + m * 16) * 32 + kread);
#pragma unroll
    for (int n = 0; n < 4; ++n)
      bF[n] = *(const bfrag*)(&Bs[buf][0] + (rB + n * 16) * 32 + kread);
#pragma unroll
    for (int m = 0; m < 8; ++m)
#pragma unroll
      for (int n = 0; n < 4; ++n)
        acc[m][n] = __builtin_amdgcn_mfma_f32_16x16x32_bf16(aF[m], bF[n], acc[m][n], 0, 0, 0);
  }
  const int cr = (lane >> 4) << 2;
  const int cc2 = lane & 15;
#pragma unroll
  for (int m = 0; m < 8; ++m)
#pragma unroll
    for (int n = 0; n < 4; ++n) {
      int r = row0 + wr * 128 + m * 16 + cr;
      int c = col0 + wc * 64 + n * 16 + cc2;
#pragma unroll
      for (int j = 0; j < 4; ++j) {
        if constexpr (OUTMODE == 0) {
          ((unsigned short*)Cv)[(size_t)(r + j) * N + c] = f2b(acc[m][n][j]);
        } else {
          ((float*)Cv)[(size_t)blockIdx.z * M * N + (size_t)(r + j) * N + c] = acc[m][n][j];
        }
      }
    }
}

// ------------- reduce O split-K partials -> out fp32 -------------
__global__ __launch_bounds__(256) void qwen_ored(const float* __restrict__ P,
                                                 float* __restrict__ out) {
  int i = (blockIdx.x * 256 + threadIdx.x) * 4;
  f32x4 a = *(const f32x4*)(P + i);
  f32x4 b = *(const f32x4*)(P + (size_t)2048 * 2048 + i);
  f32x4 s = a + b;
  *(f32x4*)(out + i) = s;
}

// ------------- rope (r17-verified): LDS-row-staged; Cq16 -> Qb + Kswz -------------
__global__ __launch_bounds__(256) void qwen_rope(const unsigned short* __restrict__ Cq16,
                                                 const float* __restrict__ cosb,
                                                 const float* __restrict__ sinb,
                                                 const float* __restrict__ qnw,
                                                 const float* __restrict__ knw,
                                                 const float* __restrict__ qden,
                                                 const float* __restrict__ kden,
                                                 unsigned short* __restrict__ Qb,
                                                 unsigned short* __restrict__ Kswz) {
  __shared__ unsigned short SMrow[4096];
  const int s = blockIdx.x;
  const int t = threadIdx.x;
  {
    const char* src = (const char*)(Cq16 + (size_t)s * 4096);
    gload_lds16(src + t * 16, (char*)SMrow + t * 16);
    gload_lds16(src + 4096 + t * 16, (char*)SMrow + 4096 + t * 16);
  }
  __syncthreads();
  const float* cs = cosb + (size_t)s * kHD;
  const float* sn = sinb + (size_t)s * kHD;
#pragma unroll
  for (int rep = 0; rep < 8; ++rep) {
    int idx = rep * 256 + t;
    int h = idx >> 7, d = idx & 127;
    float dn = qden[s * kH + h];
    float v = b2f(SMrow[idx]) * dn * qnw[d];
    float pv = b2f(SMrow[(h << 7) + (d ^ 64)]) * dn * qnw[d ^ 64];
    float rot = (d < 64) ? -pv : pv;
    Qb[((size_t)h * kS + s) * kHD + d] = f2b(v * cs[d] + rot * sn[d]);
  }
  const int kt = s >> 6, key = s & 63;
#pragma unroll
  for (int rep = 0; rep < 4; ++rep) {
    int idx = rep * 256 + t;
    int h = idx >> 7, d = idx & 127;
    float dn = kden[s * kKVH + h];
    float v = b2f(SMrow[2048 + idx]) * dn * knw[d];
    float pv = b2f(SMrow[2048 + (h << 7) + (d ^ 64)]) * dn * knw[d ^ 64];
    float rot = (d < 64) ? -pv : pv;
    size_t rowi = ((size_t)(h * 32 + kt) * 64 + key) * 128;
    Kswz[rowi + (d ^ ((key & 7) << 3))] = f2b(v * cs[d] + rot * sn[d]);
  }
}

// ------------- V -> pre-swizzled V^T tiles (bf16 in) -------------
__global__ __launch_bounds__(256) void qwen_vtr(const unsigned short* __restrict__ Cq16,
                                                unsigned short* __restrict__ Vswz) {
  __shared__ unsigned short t[64][66];
  int kvh = blockIdx.x, st = blockIdx.y, dt = blockIdx.z;
  int s0 = st * 64, d0 = dt * 64;
  int tr = threadIdx.x >> 6, tc = threadIdx.x & 63;
#pragma unroll
  for (int p = 0; p < 16; ++p) {
    int i = p * 4 + tr;
    t[i][tc] = Cq16[(size_t)(s0 + i) * 4096 + 3072 + (kvh << 7) + d0 + tc];
  }
  __syncthreads();
#pragma unroll
  for (int p = 0; p < 16; ++p) {
    int i = p * 4 + tr;
    int d = d0 + i;
    size_t rowi = ((size_t)(kvh * 32 + st) * 128 + d) * 64;
    Vswz[rowi + (tc ^ ((d & 15) << 2))] = t[tc][i];
  }
}

// ------------- attention v13 (r18-verified): dual-Q 32q/wave + key-parity split -------------
#define STAGE8(cc, bb)                                                 \
  do {                                                                 \
    const char* ks_ = Ksrc + ((size_t)(cc) << 14) + tid * 16;          \
    const char* vs_ = Vsrc + ((size_t)(cc) << 14) + tid * 16;          \
    char* kd_ = (char*)(&KV[bb][0]) + tid * 16;                        \
    char* vd_ = (char*)(&KV[2 + (bb)][0]) + tid * 16;                  \
    _Pragma("unroll") for (int it = 0; it < 4; ++it) {                 \
      gload_lds16(ks_ + it * 4096, kd_ + it * 4096);                   \
      gload_lds16(vs_ + it * 4096, vd_ + it * 4096);                   \
    }                                                                  \
  } while (0)

__global__ __launch_bounds__(256, 2) void qwen_attn(const unsigned short* __restrict__ Qb,
                                                    const unsigned short* __restrict__ Kswz,
                                                    const unsigned short* __restrict__ Vswz,
                                                    const float* __restrict__ rd,
                                                    float* __restrict__ Pacc) {
  __shared__ unsigned short KV[4][8192];
  const int bid = blockIdx.x;
  const int kvh = bid & 7;
  const int x = bid >> 3;
  const int half = x >> 5;
  const int x5 = x & 31;
  const int hb = x5 >> 4;
  const int t0 = x5 & 15;
  const int qt = half ? t0 : (15 - t0);
  const int parity = half;
  const int h = kvh * 2 + hb;
  const int q0 = qt * 128;
  const int nlc = qt + 1;
  const int tid = threadIdx.x, lane = tid & 63, w = tid >> 6;
  const int l15 = lane & 15, g = lane >> 4;
  const int qw0 = q0 + w * 32;
  const int qlim0 = qw0 + l15;
  const int qlim1 = qw0 + 16 + l15;
  const int swzK = (l15 & 7) << 3;
  const int swzV = l15 << 2;

  bfrag qF[2][4];
#pragma unroll
  for (int qs = 0; qs < 2; ++qs)
#pragma unroll
    for (int dc = 0; dc < 4; ++dc)
      qF[qs][dc] = *(const bfrag*)(Qb + ((size_t)h * kS + qw0 + qs * 16 + l15) * kHD +
                                   dc * 32 + g * 8);
  const float inv[2] = {1.0f / rd[(size_t)h * kS + qlim0],
                        1.0f / rd[(size_t)h * kS + qlim1]};

  const char* Ksrc = (const char*)Kswz + ((size_t)(kvh * 32) << 14);
  const char* Vsrc = (const char*)Vswz + ((size_t)(kvh * 32) << 14);

  f32x4 outa[2][8] = {};

  STAGE8(parity, 0);
#pragma unroll 1
  for (int lc = 0; lc < nlc; ++lc) {
    const int c = parity + 2 * lc;
    const int b = lc & 1;
    asm volatile("s_waitcnt vmcnt(0)" ::: "memory");
    __builtin_amdgcn_s_barrier();
    if (lc + 1 < nlc) STAGE8(c + 2, b ^ 1);
    __builtin_amdgcn_s_setprio(1);
    const unsigned short* Kbuf = &KV[b][0];
    const unsigned short* Vbuf = &KV[2 + b][0];
    f32x4 sc[2][4] = {};
#pragma unroll
    for (int t4 = 0; t4 < 4; ++t4) {
      const unsigned short* kr = Kbuf + (t4 * 16 + l15) * 128;
#pragma unroll
      for (int dc = 0; dc < 4; ++dc) {
        bfrag kf = *(const bfrag*)(kr + ((dc * 32 + g * 8) ^ swzK));
        sc[0][t4] = __builtin_amdgcn_mfma_f32_16x16x32_bf16(kf, qF[0][dc], sc[0][t4], 0, 0, 0);
        sc[1][t4] = __builtin_amdgcn_mfma_f32_16x16x32_bf16(kf, qF[1][dc], sc[1][t4], 0, 0, 0);
      }
    }
    const int kbase = c * 64;
    const bool full = (kbase + 63 <= qw0);
    union { bfrag f; unsigned u[4]; } pb[2][2];
#pragma unroll
    for (int qs = 0; qs < 2; ++qs) {
      const int ql = qs ? qlim1 : qlim0;
      const float iv = inv[qs];
#pragma unroll
      for (int t4 = 0; t4 < 4; ++t4) {
        unsigned short bb[4];
#pragma unroll
        for (int rr = 0; rr < 4; ++rr) {
          float tt = sc[qs][t4][rr] * kScale;
          int key = kbase + t4 * 16 + g * 4 + rr;
          tt += (full || key <= ql) ? 7.0f : 0.0f;
          float y = tt * iv;
          float y2 = y * y, y4 = y2 * y2;
          bb[rr] = f2b(y4 * y4);
        }
        pb[qs][t4 >> 1].u[(t4 & 1) * 2 + 0] = (unsigned)bb[0] | ((unsigned)bb[1] << 16);
        pb[qs][t4 >> 1].u[(t4 & 1) * 2 + 1] = (unsigned)bb[2] | ((unsigned)bb[3] << 16);
      }
    }
#pragma unroll
    for (int dt = 0; dt < 8; ++dt) {
      const unsigned short* vr = Vbuf + (dt * 16 + l15) * 64;
#pragma unroll
      for (int pr = 0; pr < 2; ++pr) {
        union { bfrag f; short4v h4[2]; } va;
        va.h4[0] = *(const short4v*)(vr + ((pr * 32 + g * 4) ^ swzV));
        va.h4[1] = *(const short4v*)(vr + ((pr * 32 + 16 + g * 4) ^ swzV));
        outa[0][dt] = __builtin_amdgcn_mfma_f32_16x16x32_bf16(va.f, pb[0][pr].f, outa[0][dt], 0, 0, 0);
        outa[1][dt] = __builtin_amdgcn_mfma_f32_16x16x32_bf16(va.f, pb[1][pr].f, outa[1][dt], 0, 0, 0);
      }
    }
    __builtin_amdgcn_s_setprio(0);
  }
  {
    float* Po = Pacc + (((size_t)(h * 16 + qt) * 2 + parity) << 14);
#pragma unroll
    for (int qs = 0; qs < 2; ++qs) {
      const int qrow = w * 32 + qs * 16 + l15;
#pragma unroll
      for (int dt = 0; dt < 8; ++dt) {
        f32x4 v = outa[qs][dt];
        *(f32x4*)(Po + qrow * 128 + dt * 16 + g * 4) = v;
      }
    }
  }
}

// ------------- reduce attn parity partials -> AO bf16 (GEMM-swizzled) -------------
__global__ __launch_bounds__(256) void qwen_ared(const float* __restrict__ Pacc,
                                                 unsigned short* __restrict__ AO) {
  const int unit = blockIdx.x;           // h*16+qt
  const int h = unit >> 4, qt = unit & 15;
  const float* P0 = Pacc + ((size_t)unit << 15);
  const float* P1 = P0 + 16384;
  const int t = threadIdx.x;
#pragma unroll
  for (int i = 0; i < 16; ++i) {
    int idx = (i * 256 + t) * 4;
    f32x4 a = *(const f32x4*)(P0 + idx);
    f32x4 b = *(const f32x4*)(P1 + idx);
    int qrow = idx >> 7, d = idx & 127;
    int q = qt * 128 + qrow;
    int col = h * 128 + d;
    short4v o;
    o[0] = (short)f2b(a[0] + b[0]); o[1] = (short)f2b(a[1] + b[1]);
    o[2] = (short)f2b(a[2] + b[2]); o[3] = (short)f2b(a[3] + b[3]);
    *(short4v*)(AO + (size_t)q * kD + (col ^ ((q & 3) << 3))) = o;
  }
}

extern "C" void kernel_launch(void* const* d_in, const int* in_sizes, int n_in,
                              void* d_out, int out_size, void* d_ws, size_t ws_size,
                              hipStream_t stream) {
  (void)in_sizes; (void)n_in; (void)out_size; (void)ws_size;
  const float* hidden = (const float*)d_in[0];
  const float* cosb   = (const float*)d_in[1];
  const float* sinb   = (const float*)d_in[2];
  const float* qw     = (const float*)d_in[3];
  const float* kw     = (const float*)d_in[4];
  const float* vw     = (const float*)d_in[5];
  const float* ow     = (const float*)d_in[6];
  const float* qnw    = (const float*)d_in[7];
  const float* knw    = (const float*)d_in[8];
  const float* qden   = (const float*)d_in[9];
  const float* kden   = (const float*)d_in[10];
  const float* rd     = (const float*)d_in[11];
  float* out = (float*)d_out;

  char* ws = (char*)d_ws;
  unsigned short* hsb  = (unsigned short*)(ws + 0 * MB);   //  8 MB
  unsigned short* Wt   = (unsigned short*)(ws + 8 * MB);   // 16 MB
  unsigned short* Cq16 = (unsigned short*)(ws + 24 * MB);  // 16 MB bf16 [s][4096]
  float*          Pacc = (float*)(ws + 24 * MB);           // 32 MB (overlays dead Cq16)
  float*          Pocc = (float*)(ws + 24 * MB);           // 32 MB (overlays dead Pacc)
  unsigned short* Qb   = (unsigned short*)(ws + 56 * MB);  //  8 MB
  unsigned short* Kswz = (unsigned short*)(ws + 64 * MB);  //  4 MB
  unsigned short* Vswz = (unsigned short*)(ws + 68 * MB);  //  4 MB
  unsigned short* AO   = (unsigned short*)(ws + 72 * MB);  //  8 MB
  unsigned short* Ot   = (unsigned short*)(ws + 80 * MB);  //  8 MB

  qwen_cast_bf16<<<4096, 256, 0, stream>>>(hidden, hsb, 2048 * 2048 / 4);
  qwen_tw<<<dim3(32, 32), 256, 0, stream>>>(qw, 2048, 2048, Wt, 2048);
  qwen_tw<<<dim3(16, 32), 256, 0, stream>>>(kw, 2048, 1024, Wt + (size_t)2048 * 2048, 2048);
  qwen_tw<<<dim3(16, 32), 256, 0, stream>>>(vw, 2048, 1024, Wt + (size_t)3072 * 2048, 2048);
  qwen_tw<<<dim3(32, 32), 256, 0, stream>>>(ow, 2048, 2048, Ot, 2048);
  qwen_gemm_big<0><<<dim3(8, 32, 1), 256, 0, stream>>>(hsb, Wt, Cq16, 2048, 4096, 2048, 2048);
  qwen_rope<<<2048, 256, 0, stream>>>(Cq16, cosb, sinb, qnw, knw, qden, kden, Qb, Kswz);
  qwen_vtr<<<dim3(8, 32, 2), 256, 0, stream>>>(Cq16, Vswz);
  qwen_attn<<<512, 256, 0, stream>>>(Qb, Kswz, Vswz, rd, Pacc);
  qwen_ared<<<256, 256, 0, stream>>>(Pacc, AO);
  qwen_gemm_big<1><<<dim3(8, 16, 2), 256, 0, stream>>>(AO, Ot, Pocc, 2048, 2048, 2048, 1024);
  qwen_ored<<<4096, 256, 0, stream>>>(Pocc, out);
}

// Round 20
// 155.064 us; speedup vs baseline: 1.3062x; 1.3062x over previous
//
#include <hip/hip_runtime.h>
#include <cstdint>
#include <cstddef>

// Qwen3AttentionModified: B=1 S=2048 D=2048 H=16 KVH=8 HD=128
// v20: GEMMs = r18 2-phase structure with BK=64 (half the steps -> half the
// barrier/drain overhead, the m233-documented 2-phase cost). LDS 64KB (BM=128),
// 2 blocks/CU, frags processed per 32-k-slice (VGPR flat). Producers unchanged.
// attn v13 (dual-Q + key-parity), ared, rope, vtr, cast, tw: r18-verified.

namespace {
constexpr int kS = 2048;
constexpr int kD = 2048;
constexpr int kH = 16;
constexpr int kKVH = 8;
constexpr int kHD = 128;
constexpr float kScale = 0.08838834764831845f;  // 128^-0.5
constexpr size_t MB = 1u << 20;
}  // namespace

using f32x4 = __attribute__((ext_vector_type(4))) float;
using bfrag = __attribute__((ext_vector_type(8))) short;   // 8 x bf16 (16B)
using float4v = __attribute__((ext_vector_type(4))) float;
using short4v = __attribute__((ext_vector_type(4))) short;

__device__ __forceinline__ unsigned short f2b(float f) {
  union { float f; unsigned u; } x; x.f = f;
  unsigned r = x.u + 0x7FFFu + ((x.u >> 16) & 1u);  // RNE
  return (unsigned short)(r >> 16);
}

__device__ __forceinline__ float b2f(unsigned short u) {
  union { unsigned u; float f; } x; x.u = ((unsigned)u) << 16;
  return x.f;
}

__device__ __forceinline__ void gload_lds16(const void* g, void* l) {
  __builtin_amdgcn_global_load_lds(
      (const __attribute__((address_space(1))) unsigned*)g,
      (__attribute__((address_space(3))) unsigned*)l, 16, 0, 0);
}

// ---------------- cast fp32 -> bf16, GEMM-swizzled store ----------------
__global__ __launch_bounds__(256) void qwen_cast_bf16(const float* __restrict__ in,
                                                      unsigned short* __restrict__ out,
                                                      int n4) {
  int i = blockIdx.x * 256 + threadIdx.x;
  if (i >= n4) return;
  float4v v = *(const float4v*)(in + (size_t)i * 4);
  short4v o;
  o[0] = (short)f2b(v[0]); o[1] = (short)f2b(v[1]);
  o[2] = (short)f2b(v[2]); o[3] = (short)f2b(v[3]);
  int i4 = i * 4;
  int row = i4 >> 11, col = i4 & 2047;
  int scol = col ^ ((row & 3) << 3);
  *(short4v*)(out + ((size_t)row << 11) + scol) = o;
}

// ------------- transpose + cast: fp32 [R][C] -> bf16 [C][ldo], swizzled store -------------
__global__ __launch_bounds__(256) void qwen_tw(const float* __restrict__ in, int R, int C,
                                               unsigned short* __restrict__ out, int ldo) {
  __shared__ float t[64][65];
  int c0 = blockIdx.x * 64, r0 = blockIdx.y * 64;
  int tr = threadIdx.x >> 6, tc = threadIdx.x & 63;
#pragma unroll
  for (int p = 0; p < 16; ++p) {
    int i = p * 4 + tr;
    t[i][tc] = in[(size_t)(r0 + i) * C + c0 + tc];
  }
  __syncthreads();
#pragma unroll
  for (int p = 0; p < 16; ++p) {
    int i = p * 4 + tr;
    int orow = c0 + i;
    int ocol = r0 + tc;
    int scol = ocol ^ ((orow & 3) << 3);
    out[(size_t)orow * ldo + scol] = f2b(t[tc][i]);
  }
}

// ------------- GEMM v20: 2-phase dbuf, BK=64, counted drain, XCD swizzle -------------
// Inputs A/Bt stored with col^((row&3)<<3) within each 32-col K-group; LDS rows
// are 64 elems = two such groups; staging linear; frag reads XOR back per group.
template <int BM, bool BF16OUT>
__global__ __launch_bounds__(256) void qwen_gemm_bt(const unsigned short* __restrict__ A,
                                                    const unsigned short* __restrict__ Bt,
                                                    void* __restrict__ Cv,
                                                    int M, int N, int K) {
  __shared__ unsigned short As[2][BM * 64];
  __shared__ unsigned short Bs[2][128 * 64];
  constexpr int MR = BM / 32;
  const int nwg = gridDim.x * gridDim.y;
  int lin = blockIdx.y * gridDim.x + blockIdx.x;
  if ((nwg & 7) == 0) { int qq = nwg >> 3; lin = (lin & 7) * qq + (lin >> 3); }
  const int bxx = lin % gridDim.x, byy = lin / gridDim.x;
  const int tid = threadIdx.x, lane = tid & 63, w = tid >> 6;
  const int wr = w >> 1, wc = w & 1;
  const int row0 = bxx * BM, col0 = byy * 128;
  f32x4 acc[MR][4] = {};
  const int koff = (lane >> 4) << 3;
  const int kread = koff ^ ((lane & 3) << 3);
  const int rA = wr * (BM / 2) + (lane & 15);
  const int rB = wc * 64 + (lane & 15);

  auto stage = [&](int kt, int b) {
#pragma unroll
    for (int c = 0; c < BM / 32; ++c) {  // A: BM rows x 64 elems (BM*128 bytes)
      int off = (c * 256 + tid) * 16;
      int e = off >> 1;
      int r = e >> 6, cc = e & 63;
      gload_lds16(A + (size_t)(row0 + r) * K + kt + cc, (char*)(&As[b][0]) + off);
    }
#pragma unroll
    for (int c = 0; c < 4; ++c) {        // B: 128 rows x 64 elems
      int off = (c * 256 + tid) * 16;
      int e = off >> 1;
      int r = e >> 6, cc = e & 63;
      gload_lds16(Bt + (size_t)(col0 + r) * K + kt + cc, (char*)(&Bs[b][0]) + off);
    }
  };

  const int nk = K >> 6;  // BK=64 steps
  stage(0, 0);
  asm volatile("s_waitcnt vmcnt(0)" ::: "memory");
  __builtin_amdgcn_s_barrier();
  int buf = 0;
#pragma unroll 1
  for (int t = 0; t < nk; ++t) {
    if (t + 1 < nk) stage((t + 1) << 6, buf ^ 1);  // next tile in flight across compute
#pragma unroll
    for (int kc = 0; kc < 2; ++kc) {  // two 32-k slices; frag regs reused
      bfrag aF[MR], bF[4];
#pragma unroll
      for (int m = 0; m < MR; ++m)
        aF[m] = *(const bfrag*)(&As[buf][0] + (rA + m * 16) * 64 + kc * 32 + kread);
#pragma unroll
      for (int n = 0; n < 4; ++n)
        bF[n] = *(const bfrag*)(&Bs[buf][0] + (rB + n * 16) * 64 + kc * 32 + kread);
#pragma unroll
      for (int m = 0; m < MR; ++m)
#pragma unroll
        for (int n = 0; n < 4; ++n)
          acc[m][n] = __builtin_amdgcn_mfma_f32_16x16x32_bf16(aF[m], bF[n], acc[m][n], 0, 0, 0);
    }
    asm volatile("s_waitcnt vmcnt(0)" ::: "memory");  // next tile landed (overlapped)
    __builtin_amdgcn_s_barrier();
    buf ^= 1;
  }
  const int cr = (lane >> 4) << 2;
  const int cc2 = lane & 15;
#pragma unroll
  for (int m = 0; m < MR; ++m)
#pragma unroll
    for (int n = 0; n < 4; ++n) {
      int r = row0 + wr * (BM / 2) + m * 16 + cr;
      int c = col0 + wc * 64 + n * 16 + cc2;
#pragma unroll
      for (int j = 0; j < 4; ++j) {
        if constexpr (BF16OUT) {
          ((unsigned short*)Cv)[(size_t)(r + j) * N + c] = f2b(acc[m][n][j]);
        } else {
          ((float*)Cv)[(size_t)(r + j) * N + c] = acc[m][n][j];
        }
      }
    }
}

// ------------- rope (r17-verified): LDS-row-staged; Cq16 -> Qb + Kswz -------------
__global__ __launch_bounds__(256) void qwen_rope(const unsigned short* __restrict__ Cq16,
                                                 const float* __restrict__ cosb,
                                                 const float* __restrict__ sinb,
                                                 const float* __restrict__ qnw,
                                                 const float* __restrict__ knw,
                                                 const float* __restrict__ qden,
                                                 const float* __restrict__ kden,
                                                 unsigned short* __restrict__ Qb,
                                                 unsigned short* __restrict__ Kswz) {
  __shared__ unsigned short SMrow[4096];
  const int s = blockIdx.x;
  const int t = threadIdx.x;
  {
    const char* src = (const char*)(Cq16 + (size_t)s * 4096);
    gload_lds16(src + t * 16, (char*)SMrow + t * 16);
    gload_lds16(src + 4096 + t * 16, (char*)SMrow + 4096 + t * 16);
  }
  __syncthreads();
  const float* cs = cosb + (size_t)s * kHD;
  const float* sn = sinb + (size_t)s * kHD;
#pragma unroll
  for (int rep = 0; rep < 8; ++rep) {
    int idx = rep * 256 + t;
    int h = idx >> 7, d = idx & 127;
    float dn = qden[s * kH + h];
    float v = b2f(SMrow[idx]) * dn * qnw[d];
    float pv = b2f(SMrow[(h << 7) + (d ^ 64)]) * dn * qnw[d ^ 64];
    float rot = (d < 64) ? -pv : pv;
    Qb[((size_t)h * kS + s) * kHD + d] = f2b(v * cs[d] + rot * sn[d]);
  }
  const int kt = s >> 6, key = s & 63;
#pragma unroll
  for (int rep = 0; rep < 4; ++rep) {
    int idx = rep * 256 + t;
    int h = idx >> 7, d = idx & 127;
    float dn = kden[s * kKVH + h];
    float v = b2f(SMrow[2048 + idx]) * dn * knw[d];
    float pv = b2f(SMrow[2048 + (h << 7) + (d ^ 64)]) * dn * knw[d ^ 64];
    float rot = (d < 64) ? -pv : pv;
    size_t rowi = ((size_t)(h * 32 + kt) * 64 + key) * 128;
    Kswz[rowi + (d ^ ((key & 7) << 3))] = f2b(v * cs[d] + rot * sn[d]);
  }
}

// ------------- V -> pre-swizzled V^T tiles (bf16 in) -------------
__global__ __launch_bounds__(256) void qwen_vtr(const unsigned short* __restrict__ Cq16,
                                                unsigned short* __restrict__ Vswz) {
  __shared__ unsigned short t[64][66];
  int kvh = blockIdx.x, st = blockIdx.y, dt = blockIdx.z;
  int s0 = st * 64, d0 = dt * 64;
  int tr = threadIdx.x >> 6, tc = threadIdx.x & 63;
#pragma unroll
  for (int p = 0; p < 16; ++p) {
    int i = p * 4 + tr;
    t[i][tc] = Cq16[(size_t)(s0 + i) * 4096 + 3072 + (kvh << 7) + d0 + tc];
  }
  __syncthreads();
#pragma unroll
  for (int p = 0; p < 16; ++p) {
    int i = p * 4 + tr;
    int d = d0 + i;
    size_t rowi = ((size_t)(kvh * 32 + st) * 128 + d) * 64;
    Vswz[rowi + (tc ^ ((d & 15) << 2))] = t[tc][i];
  }
}

// ------------- attention v13 (r18-verified): dual-Q 32q/wave + key-parity split -------------
#define STAGE8(cc, bb)                                                 \
  do {                                                                 \
    const char* ks_ = Ksrc + ((size_t)(cc) << 14) + tid * 16;          \
    const char* vs_ = Vsrc + ((size_t)(cc) << 14) + tid * 16;          \
    char* kd_ = (char*)(&KV[bb][0]) + tid * 16;                        \
    char* vd_ = (char*)(&KV[2 + (bb)][0]) + tid * 16;                  \
    _Pragma("unroll") for (int it = 0; it < 4; ++it) {                 \
      gload_lds16(ks_ + it * 4096, kd_ + it * 4096);                   \
      gload_lds16(vs_ + it * 4096, vd_ + it * 4096);                   \
    }                                                                  \
  } while (0)

__global__ __launch_bounds__(256, 2) void qwen_attn(const unsigned short* __restrict__ Qb,
                                                    const unsigned short* __restrict__ Kswz,
                                                    const unsigned short* __restrict__ Vswz,
                                                    const float* __restrict__ rd,
                                                    float* __restrict__ Pacc) {
  __shared__ unsigned short KV[4][8192];
  const int bid = blockIdx.x;
  const int kvh = bid & 7;
  const int x = bid >> 3;
  const int half = x >> 5;
  const int x5 = x & 31;
  const int hb = x5 >> 4;
  const int t0 = x5 & 15;
  const int qt = half ? t0 : (15 - t0);
  const int parity = half;
  const int h = kvh * 2 + hb;
  const int q0 = qt * 128;
  const int nlc = qt + 1;
  const int tid = threadIdx.x, lane = tid & 63, w = tid >> 6;
  const int l15 = lane & 15, g = lane >> 4;
  const int qw0 = q0 + w * 32;
  const int qlim0 = qw0 + l15;
  const int qlim1 = qw0 + 16 + l15;
  const int swzK = (l15 & 7) << 3;
  const int swzV = l15 << 2;

  bfrag qF[2][4];
#pragma unroll
  for (int qs = 0; qs < 2; ++qs)
#pragma unroll
    for (int dc = 0; dc < 4; ++dc)
      qF[qs][dc] = *(const bfrag*)(Qb + ((size_t)h * kS + qw0 + qs * 16 + l15) * kHD +
                                   dc * 32 + g * 8);
  const float inv[2] = {1.0f / rd[(size_t)h * kS + qlim0],
                        1.0f / rd[(size_t)h * kS + qlim1]};

  const char* Ksrc = (const char*)Kswz + ((size_t)(kvh * 32) << 14);
  const char* Vsrc = (const char*)Vswz + ((size_t)(kvh * 32) << 14);

  f32x4 outa[2][8] = {};

  STAGE8(parity, 0);
#pragma unroll 1
  for (int lc = 0; lc < nlc; ++lc) {
    const int c = parity + 2 * lc;
    const int b = lc & 1;
    asm volatile("s_waitcnt vmcnt(0)" ::: "memory");
    __builtin_amdgcn_s_barrier();
    if (lc + 1 < nlc) STAGE8(c + 2, b ^ 1);
    __builtin_amdgcn_s_setprio(1);
    const unsigned short* Kbuf = &KV[b][0];
    const unsigned short* Vbuf = &KV[2 + b][0];
    f32x4 sc[2][4] = {};
#pragma unroll
    for (int t4 = 0; t4 < 4; ++t4) {
      const unsigned short* kr = Kbuf + (t4 * 16 + l15) * 128;
#pragma unroll
      for (int dc = 0; dc < 4; ++dc) {
        bfrag kf = *(const bfrag*)(kr + ((dc * 32 + g * 8) ^ swzK));
        sc[0][t4] = __builtin_amdgcn_mfma_f32_16x16x32_bf16(kf, qF[0][dc], sc[0][t4], 0, 0, 0);
        sc[1][t4] = __builtin_amdgcn_mfma_f32_16x16x32_bf16(kf, qF[1][dc], sc[1][t4], 0, 0, 0);
      }
    }
    const int kbase = c * 64;
    const bool full = (kbase + 63 <= qw0);
    union { bfrag f; unsigned u[4]; } pb[2][2];
#pragma unroll
    for (int qs = 0; qs < 2; ++qs) {
      const int ql = qs ? qlim1 : qlim0;
      const float iv = inv[qs];
#pragma unroll
      for (int t4 = 0; t4 < 4; ++t4) {
        unsigned short bb[4];
#pragma unroll
        for (int rr = 0; rr < 4; ++rr) {
          float tt = sc[qs][t4][rr] * kScale;
          int key = kbase + t4 * 16 + g * 4 + rr;
          tt += (full || key <= ql) ? 7.0f : 0.0f;
          float y = tt * iv;
          float y2 = y * y, y4 = y2 * y2;
          bb[rr] = f2b(y4 * y4);
        }
        pb[qs][t4 >> 1].u[(t4 & 1) * 2 + 0] = (unsigned)bb[0] | ((unsigned)bb[1] << 16);
        pb[qs][t4 >> 1].u[(t4 & 1) * 2 + 1] = (unsigned)bb[2] | ((unsigned)bb[3] << 16);
      }
    }
#pragma unroll
    for (int dt = 0; dt < 8; ++dt) {
      const unsigned short* vr = Vbuf + (dt * 16 + l15) * 64;
#pragma unroll
      for (int pr = 0; pr < 2; ++pr) {
        union { bfrag f; short4v h4[2]; } va;
        va.h4[0] = *(const short4v*)(vr + ((pr * 32 + g * 4) ^ swzV));
        va.h4[1] = *(const short4v*)(vr + ((pr * 32 + 16 + g * 4) ^ swzV));
        outa[0][dt] = __builtin_amdgcn_mfma_f32_16x16x32_bf16(va.f, pb[0][pr].f, outa[0][dt], 0, 0, 0);
        outa[1][dt] = __builtin_amdgcn_mfma_f32_16x16x32_bf16(va.f, pb[1][pr].f, outa[1][dt], 0, 0, 0);
      }
    }
    __builtin_amdgcn_s_setprio(0);
  }
  {
    float* Po = Pacc + (((size_t)(h * 16 + qt) * 2 + parity) << 14);
#pragma unroll
    for (int qs = 0; qs < 2; ++qs) {
      const int qrow = w * 32 + qs * 16 + l15;
#pragma unroll
      for (int dt = 0; dt < 8; ++dt) {
        f32x4 v = outa[qs][dt];
        *(f32x4*)(Po + qrow * 128 + dt * 16 + g * 4) = v;
      }
    }
  }
}

// ------------- reduce attn parity partials -> AO bf16 (GEMM-swizzled) -------------
__global__ __launch_bounds__(256) void qwen_ared(const float* __restrict__ Pacc,
                                                 unsigned short* __restrict__ AO) {
  const int unit = blockIdx.x;           // h*16+qt
  const int h = unit >> 4, qt = unit & 15;
  const float* P0 = Pacc + ((size_t)unit << 15);
  const float* P1 = P0 + 16384;
  const int t = threadIdx.x;
#pragma unroll
  for (int i = 0; i < 16; ++i) {
    int idx = (i * 256 + t) * 4;
    f32x4 a = *(const f32x4*)(P0 + idx);
    f32x4 b = *(const f32x4*)(P1 + idx);
    int qrow = idx >> 7, d = idx & 127;
    int q = qt * 128 + qrow;
    int col = h * 128 + d;
    short4v o;
    o[0] = (short)f2b(a[0] + b[0]); o[1] = (short)f2b(a[1] + b[1]);
    o[2] = (short)f2b(a[2] + b[2]); o[3] = (short)f2b(a[3] + b[3]);
    *(short4v*)(AO + (size_t)q * kD + (col ^ ((q & 3) << 3))) = o;
  }
}

extern "C" void kernel_launch(void* const* d_in, const int* in_sizes, int n_in,
                              void* d_out, int out_size, void* d_ws, size_t ws_size,
                              hipStream_t stream) {
  (void)in_sizes; (void)n_in; (void)out_size; (void)ws_size;
  const float* hidden = (const float*)d_in[0];
  const float* cosb   = (const float*)d_in[1];
  const float* sinb   = (const float*)d_in[2];
  const float* qw     = (const float*)d_in[3];
  const float* kw     = (const float*)d_in[4];
  const float* vw     = (const float*)d_in[5];
  const float* ow     = (const float*)d_in[6];
  const float* qnw    = (const float*)d_in[7];
  const float* knw    = (const float*)d_in[8];
  const float* qden   = (const float*)d_in[9];
  const float* kden   = (const float*)d_in[10];
  const float* rd     = (const float*)d_in[11];
  float* out = (float*)d_out;

  char* ws = (char*)d_ws;
  unsigned short* hsb  = (unsigned short*)(ws + 0 * MB);   //  8 MB
  unsigned short* Wt   = (unsigned short*)(ws + 8 * MB);   // 16 MB
  unsigned short* Cq16 = (unsigned short*)(ws + 24 * MB);  // 16 MB bf16 [s][4096]
  float*          Pacc = (float*)(ws + 24 * MB);           // 32 MB (overlays dead Cq16)
  unsigned short* Qb   = (unsigned short*)(ws + 56 * MB);  //  8 MB
  unsigned short* Kswz = (unsigned short*)(ws + 64 * MB);  //  4 MB
  unsigned short* Vswz = (unsigned short*)(ws + 68 * MB);  //  4 MB
  unsigned short* AO   = (unsigned short*)(ws + 72 * MB);  //  8 MB
  unsigned short* Ot   = (unsigned short*)(ws + 80 * MB);  //  8 MB

  qwen_cast_bf16<<<4096, 256, 0, stream>>>(hidden, hsb, 2048 * 2048 / 4);
  qwen_tw<<<dim3(32, 32), 256, 0, stream>>>(qw, 2048, 2048, Wt, 2048);
  qwen_tw<<<dim3(16, 32), 256, 0, stream>>>(kw, 2048, 1024, Wt + (size_t)2048 * 2048, 2048);
  qwen_tw<<<dim3(16, 32), 256, 0, stream>>>(vw, 2048, 1024, Wt + (size_t)3072 * 2048, 2048);
  qwen_tw<<<dim3(32, 32), 256, 0, stream>>>(ow, 2048, 2048, Ot, 2048);
  qwen_gemm_bt<128, true><<<dim3(16, 32), 256, 0, stream>>>(hsb, Wt, Cq16, 2048, 4096, 2048);
  qwen_rope<<<2048, 256, 0, stream>>>(Cq16, cosb, sinb, qnw, knw, qden, kden, Qb, Kswz);
  qwen_vtr<<<dim3(8, 32, 2), 256, 0, stream>>>(Cq16, Vswz);
  qwen_attn<<<512, 256, 0, stream>>>(Qb, Kswz, Vswz, rd, Pacc);
  qwen_ared<<<256, 256, 0, stream>>>(Pacc, AO);
  qwen_gemm_bt<64, false><<<dim3(32, 16), 256, 0, stream>>>(AO, Ot, out, 2048, 2048, 2048);
}